// Round 9
// baseline (38.977 us; speedup 1.0000x reference)
//
#include <hip/hip_runtime.h>

// out[s,d,b,j] = log( sum_i exp(x[s,d,b,i]) * acc[s,d,i,j] ) - log( sum_i acc[s,d,i,j] )
// 256 batched 256x256x256 GEMMs in linear space, bf16 MFMA, fp32 accumulate.
// Grid 512: block = (sd = bid&255, jhalf = bid>>8); 80 KB LDS -> 2 blocks/CU =
// two independent barrier domains per CU (TLP across blocks). Persistent-B half
// [128j][256k] bf16 in LDS. logS computed via ones-row MFMA (no LDS reduce).

#define NB  256
#define NI  256
#define NJ  256
#define JH  128   // j columns per block
#define PH  128   // b rows per pass

typedef __attribute__((ext_vector_type(8))) short bf16x8;
typedef __attribute__((ext_vector_type(4))) float f32x4;

__device__ __forceinline__ unsigned short f2bf(float f) {
  unsigned int u = __float_as_uint(f);
  u += 0x7FFFu + ((u >> 16) & 1u);
  return (unsigned short)(u >> 16);
}

__global__ __launch_bounds__(512, 4)
void densesum_kernel(const float* __restrict__ x,
                     const float* __restrict__ acc,
                     float* __restrict__ out) {
  const int bid = blockIdx.x;
  const int sd  = bid & 255;                 // pair (sd, sd+256): same XCD L2
  const int j0  = (bid >> 8) * JH;
  const float* xb  = x   + (size_t)sd * NB * NI;
  const float* xb2 = xb  + (size_t)PH * NI;
  const float* ab  = acc + (size_t)sd * NI * NJ + j0;
  float*       ob  = out + (size_t)sd * NB * NJ + j0;

  // As: per-pass A [128 b][64 k] bf16 (16 KB), swizzle (b&7)<<3.
  // Bs: persistent B^T half [128 j][256 k] bf16 (64 KB), swizzle (j&7)<<3.
  // Total 80 KB exactly -> 2 blocks/CU.
  __shared__ unsigned short As[PH * 64];
  __shared__ unsigned short Bs[JH * NI];

  const int tid  = threadIdx.x;
  const int lane = tid & 63;
  const int wid  = tid >> 6;      // 8 waves
  const int wr   = wid >> 2;      // 0..1  (64-row strip of local b)
  const int wc   = wid & 3;       // 0..3  (32-col strip of local j)
  const int l15  = lane & 15;
  const int lk   = lane >> 4;     // 0..3
  const int r    = (lane >> 1) & 3;   // B write-order rotation
  const bool s1 = (r & 1), s2 = (r & 2);

  f32x4 C[4][2];                  // main accumulator (64b x 32j per wave)
  f32x4 CS[2];                    // ones-row accumulator -> column sums S_j
  float4 pa[4];                   // A prefetch: 128 b x 64 k / 512 thr
  float4 pb[4];                   // B prefetch: 64 k x 128 j / 512 thr

  bf16x8 onesf;
  #pragma unroll
  for (int e = 0; e < 8; ++e) onesf[e] = (short)0x3F80;   // bf16 1.0

  auto zeroC = [&]() {
    #pragma unroll
    for (int m = 0; m < 4; ++m)
      #pragma unroll
      for (int n = 0; n < 2; ++n)
        C[m][n] = (f32x4){0.f, 0.f, 0.f, 0.f};
  };

  auto loadA = [&](const float* xh, int kc) {
    #pragma unroll
    for (int it = 0; it < 4; ++it) {
      int q  = tid + it * 512;              // 0..2047 quads
      int b  = q >> 4;                      // 0..127
      int c0 = (q & 15) * 4;                // 0..60
      pa[it] = *reinterpret_cast<const float4*>(xh + (size_t)b * NI + kc * 64 + c0);
    }
  };
  auto loadB = [&](int kc) {
    int kl = (tid >> 5) * 4;                // 0..60, k-quad
    int jb = (tid & 31) * 4;                // 0..124, j-quad
    const float* src = ab + (size_t)(kc * 64 + kl) * NJ + jb;
    pb[0] = *reinterpret_cast<const float4*>(src);
    pb[1] = *reinterpret_cast<const float4*>(src + NJ);
    pb[2] = *reinterpret_cast<const float4*>(src + 2 * NJ);
    pb[3] = *reinterpret_cast<const float4*>(src + 3 * NJ);
  };
  auto convA = [&]() {
    #pragma unroll
    for (int it = 0; it < 4; ++it) {
      int q  = tid + it * 512;
      int b  = q >> 4;
      int c0 = (q & 15) * 4;
      ushort4 h;
      h.x = f2bf(__expf(pa[it].x));
      h.y = f2bf(__expf(pa[it].y));
      h.z = f2bf(__expf(pa[it].z));
      h.w = f2bf(__expf(pa[it].w));
      *reinterpret_cast<ushort4*>(&As[b * 64 + (c0 ^ ((b & 7) << 3))]) = h;
    }
  };
  auto convB = [&](int kc) {
    int kl = (tid >> 5) * 4;
    int jb = (tid & 31) * 4;
    int kg = kc * 64 + kl;                  // global k, multiple of 4
    float4 v0 = pb[0], v1 = pb[1], v2 = pb[2], v3 = pb[3];
    // rotate each vector left by r: u[c] = v[(c+r)&3]  (no dynamic indexing)
    #define ROT(v, u0, u1, u2, u3)                                              \
      { float t0 = s1 ? v.y : v.x, t1 = s1 ? v.z : v.y,                         \
              t2 = s1 ? v.w : v.z, t3 = s1 ? v.x : v.w;                         \
        u0 = s2 ? t2 : t0; u1 = s2 ? t3 : t1;                                   \
        u2 = s2 ? t0 : t2; u3 = s2 ? t1 : t3; }
    float a00, a01, a02, a03; ROT(v0, a00, a01, a02, a03);
    float a10, a11, a12, a13; ROT(v1, a10, a11, a12, a13);
    float a20, a21, a22, a23; ROT(v2, a20, a21, a22, a23);
    float a30, a31, a32, a33; ROT(v3, a30, a31, a32, a33);
    #undef ROT
    // column cc: jc = jb + ((cc+r)&3); k-quad contiguous after swizzle (kg%4==0)
    #define STORE_COL(cc, w0, w1, w2, w3)                                       \
      { int jc = jb + ((cc + r) & 3);                                           \
        ushort4 h; h.x = f2bf(w0); h.y = f2bf(w1);                              \
        h.z = f2bf(w2); h.w = f2bf(w3);                                         \
        *reinterpret_cast<ushort4*>(&Bs[jc * NI + (kg ^ ((jc & 7) << 3))]) = h; }
    STORE_COL(0, a00, a10, a20, a30);
    STORE_COL(1, a01, a11, a21, a31);
    STORE_COL(2, a02, a12, a22, a32);
    STORE_COL(3, a03, a13, a23, a33);
    #undef STORE_COL
  };
  // pass-1 MFMA: main tiles + ones-row column-sum accumulation
  auto mfmaChunkS = [&](int kc) {
    #pragma unroll
    for (int ks = 0; ks < 2; ++ks) {
      const int ka = ks * 32 + 8 * lk;            // k within As (64-col rows)
      const int kg = kc * 64 + ka;                // k within Bs (256-col rows)
      bf16x8 bfr[2];
      #pragma unroll
      for (int n = 0; n < 2; ++n) {
        int row = wc * 32 + n * 16 + l15;
        bfr[n] = *reinterpret_cast<const bf16x8*>(&Bs[row * NI + (kg ^ ((row & 7) << 3))]);
      }
      #pragma unroll
      for (int n = 0; n < 2; ++n)
        CS[n] = __builtin_amdgcn_mfma_f32_16x16x32_bf16(onesf, bfr[n], CS[n], 0, 0, 0);
      #pragma unroll
      for (int m = 0; m < 4; ++m) {
        int row = wr * 64 + m * 16 + l15;
        bf16x8 af = *reinterpret_cast<const bf16x8*>(&As[row * 64 + (ka ^ ((row & 7) << 3))]);
        #pragma unroll
        for (int n = 0; n < 2; ++n)
          C[m][n] = __builtin_amdgcn_mfma_f32_16x16x32_bf16(af, bfr[n], C[m][n], 0, 0, 0);
      }
    }
  };
  auto mfmaChunk = [&](int kc) {
    #pragma unroll
    for (int ks = 0; ks < 2; ++ks) {
      const int ka = ks * 32 + 8 * lk;
      const int kg = kc * 64 + ka;
      bf16x8 bfr[2];
      #pragma unroll
      for (int n = 0; n < 2; ++n) {
        int row = wc * 32 + n * 16 + l15;
        bfr[n] = *reinterpret_cast<const bf16x8*>(&Bs[row * NI + (kg ^ ((row & 7) << 3))]);
      }
      #pragma unroll
      for (int m = 0; m < 4; ++m) {
        int row = wr * 64 + m * 16 + l15;
        bf16x8 af = *reinterpret_cast<const bf16x8*>(&As[row * 64 + (ka ^ ((row & 7) << 3))]);
        #pragma unroll
        for (int n = 0; n < 2; ++n)
          C[m][n] = __builtin_amdgcn_mfma_f32_16x16x32_bf16(af, bfr[n], C[m][n], 0, 0, 0);
      }
    }
  };
  auto epilogue = [&](int p, float ls0, float ls1) {
    float* obp = ob + (size_t)p * PH * NJ;
    #pragma unroll
    for (int m = 0; m < 4; ++m) {
      int b0 = wr * 64 + m * 16 + lk * 4;
      #pragma unroll
      for (int n = 0; n < 2; ++n) {
        int j = wc * 32 + n * 16 + l15;
        float ls = n ? ls1 : ls0;
        #pragma unroll
        for (int rr = 0; rr < 4; ++rr) {
          obp[(size_t)(b0 + rr) * NJ + j] = __logf(C[m][n][rr]) - ls;
        }
      }
    }
  };

  // ================= pass 1: b-rows 0..127, stage B persistently =================
  loadA(xb, 0);
  loadB(0);
  zeroC();
  CS[0] = (f32x4){0.f, 0.f, 0.f, 0.f};
  CS[1] = (f32x4){0.f, 0.f, 0.f, 0.f};
  for (int kc = 0; kc < 4; ++kc) {
    convA();
    convB(kc);
    __syncthreads();
    if (kc < 3) {            // loads fly across the MFMA phase and the barrier
      loadA(xb, kc + 1);
      loadB(kc + 1);
    } else {                 // prefetch pass-2 chunk 0 (A only)
      loadA(xb2, 0);
    }
    mfmaChunkS(kc);
    __syncthreads();
  }

  // ---- column sums from ones-row MFMA: lane already holds S_j for its own j
  const float ls0 = __logf(CS[0][0]);
  const float ls1 = __logf(CS[1][0]);

  // ---- epilogue half 0 (pass-2 chunk-0 loads already in flight; no LDS use)
  epilogue(0, ls0, ls1);

  // ================= pass 2: b-rows 128..255 against resident Bs =================
  zeroC();
  for (int kc = 0; kc < 4; ++kc) {
    convA();
    __syncthreads();
    if (kc < 3) loadA(xb2, kc + 1);
    mfmaChunk(kc);
    __syncthreads();
  }

  epilogue(1, ls0, ls1);
}

extern "C" void kernel_launch(void* const* d_in, const int* in_sizes, int n_in,
                              void* d_out, int out_size, void* d_ws, size_t ws_size,
                              hipStream_t stream) {
  const float* x   = (const float*)d_in[0];
  const float* acc = (const float*)d_in[1];
  float* out = (float*)d_out;
  hipLaunchKernelGGL(densesum_kernel, dim3(NB * 2), dim3(512), 0, stream, x, acc, out);
}

// Round 12
// 38.305 us; speedup vs baseline: 1.0175x; 1.0175x over previous
//
#include <hip/hip_runtime.h>

// out[s,d,b,j] = log( sum_i exp(x[s,d,b,i]) * acc[s,d,i,j] ) - log( sum_i acc[s,d,i,j] )
// 256 batched 256x256x256 GEMMs in linear space, bf16 MFMA, fp32 accumulate.
// Grid 256 (1 block/CU), 512 threads. Two-pass persistent-B (B^T bf16 in LDS, 128 KB).
// R12 = R5 schedule (proven passing) + round-half-up bf16 pack via v_perm_b32:
// 3 VALU ops per 2 elements instead of ~7 (no inline asm, no semantics risk).

#define NB  256
#define NI  256
#define NJ  256
#define BH  128

typedef __attribute__((ext_vector_type(8))) short bf16x8;
typedef __attribute__((ext_vector_type(4))) float f32x4;

// pack two positive f32 -> two bf16 (round-half-up, 0.5-ulp envelope), low = a.
// v_perm_b32(S0=ub, S1=ua, sel): bytes 0-3 pick from ua, 4-7 from ub;
// sel 0x07060302 -> D = { ub[31:24], ub[23:16], ua[31:24], ua[23:16] }.
__device__ __forceinline__ unsigned int pack_bf16(float a, float b) {
  unsigned int ua = __float_as_uint(a) + 0x8000u;
  unsigned int ub = __float_as_uint(b) + 0x8000u;
  return __builtin_amdgcn_perm(ub, ua, 0x07060302u);
}

__global__ __launch_bounds__(512, 2)
void densesum_kernel(const float* __restrict__ x,
                     const float* __restrict__ acc,
                     float* __restrict__ out) {
  const int sd = blockIdx.x;
  const float* xb  = x   + (size_t)sd * NB * NI;
  const float* xb2 = xb + (size_t)BH * NI;
  const float* ab  = acc + (size_t)sd * NI * NJ;
  float*       ob  = out + (size_t)sd * NB * NJ;

  // As: per-pass A half [128 b][64 k] bf16 (16 KB), swizzle (b&7)<<3.
  // Bs: persistent B^T [256 j][256 k] bf16 (128 KB), swizzle (j&7)<<3.
  __shared__ unsigned short As[BH * 64];
  __shared__ unsigned short Bs[NJ * NI];
  __shared__ float colpart[8 * NJ];
  __shared__ float logS[NJ];

  const int tid  = threadIdx.x;
  const int lane = tid & 63;
  const int wid  = tid >> 6;      // 8 waves
  const int wr   = wid >> 2;      // 0..1  (64-row strip of local b)
  const int wc   = wid & 3;       // 0..3  (64-col strip of j)
  const int l15  = lane & 15;
  const int lk   = lane >> 4;     // 0..3
  const int r    = (lane >> 1) & 3;   // B write-order rotation
  const bool s1 = (r & 1), s2 = (r & 2);

  f32x4 C[4][4];
  float bsum0 = 0.f, bsum1 = 0.f, bsum2 = 0.f, bsum3 = 0.f;
  float4 pa[4];   // A prefetch: 4 float4 / thread / chunk (128 b x 64 k)
  float4 pb[8];   // B prefetch: 8 float4 / thread / chunk (64 k x 256 j)

  auto zeroC = [&]() {
    #pragma unroll
    for (int m = 0; m < 4; ++m)
      #pragma unroll
      for (int n = 0; n < 4; ++n)
        C[m][n] = (f32x4){0.f, 0.f, 0.f, 0.f};
  };

  auto loadA = [&](const float* xh, int kc) {
    #pragma unroll
    for (int it = 0; it < 4; ++it) {
      int q  = tid + it * 512;              // 0..2047 quads
      int b  = q >> 4;                      // 0..127
      int c0 = (q & 15) * 4;                // 0..60
      pa[it] = *reinterpret_cast<const float4*>(xh + (size_t)b * NI + kc * 64 + c0);
    }
  };
  auto loadB = [&](int kc) {
    #pragma unroll
    for (int t = 0; t < 2; ++t) {
      int q  = tid + t * 512;               // 0..1023 tasks
      int kl = (q >> 6) * 4;                // 0..60, k-quad
      int jb = (q & 63) * 4;                // 0..252, j-quad
      const float* src = ab + (size_t)(kc * 64 + kl) * NJ + jb;
      pb[t * 4 + 0] = *reinterpret_cast<const float4*>(src);
      pb[t * 4 + 1] = *reinterpret_cast<const float4*>(src + NJ);
      pb[t * 4 + 2] = *reinterpret_cast<const float4*>(src + 2 * NJ);
      pb[t * 4 + 3] = *reinterpret_cast<const float4*>(src + 3 * NJ);
    }
  };
  auto convA = [&]() {
    #pragma unroll
    for (int it = 0; it < 4; ++it) {
      int q  = tid + it * 512;
      int b  = q >> 4;
      int c0 = (q & 15) * 4;
      uint2 h;
      h.x = pack_bf16(__expf(pa[it].x), __expf(pa[it].y));
      h.y = pack_bf16(__expf(pa[it].z), __expf(pa[it].w));
      *reinterpret_cast<uint2*>(&As[b * 64 + (c0 ^ ((b & 7) << 3))]) = h;
    }
  };
  auto convB = [&](int kc) {
    #pragma unroll
    for (int t = 0; t < 2; ++t) {
      int q   = tid + t * 512;
      int kl  = (q >> 6) * 4;
      int jb  = (q & 63) * 4;
      int kg  = kc * 64 + kl;               // global k, multiple of 4
      float4 v0 = pb[t * 4 + 0], v1 = pb[t * 4 + 1];
      float4 v2 = pb[t * 4 + 2], v3 = pb[t * 4 + 3];
      // rotate each vector left by r: u[c] = v[(c+r)&3]  (no dynamic indexing)
      #define ROT(v, u0, u1, u2, u3)                                            \
        { float t0 = s1 ? v.y : v.x, t1 = s1 ? v.z : v.y,                       \
                t2 = s1 ? v.w : v.z, t3 = s1 ? v.x : v.w;                       \
          u0 = s2 ? t2 : t0; u1 = s2 ? t3 : t1;                                 \
          u2 = s2 ? t0 : t2; u3 = s2 ? t1 : t3; }
      float a00, a01, a02, a03; ROT(v0, a00, a01, a02, a03);
      float a10, a11, a12, a13; ROT(v1, a10, a11, a12, a13);
      float a20, a21, a22, a23; ROT(v2, a20, a21, a22, a23);
      float a30, a31, a32, a33; ROT(v3, a30, a31, a32, a33);
      #undef ROT
      // column cc: jc = jb + ((cc+r)&3); values w0..w3 are k..k+3 (contiguous
      // after swizzle since kg%4==0); pack pairs via v_perm.
      #define STORE_COL(cc, w0, w1, w2, w3)                                     \
        { int jc = jb + ((cc + r) & 3);                                         \
          bsum##cc += w0 + w1 + w2 + w3;                                        \
          uint2 h;                                                              \
          h.x = pack_bf16(w0, w1);                                              \
          h.y = pack_bf16(w2, w3);                                              \
          *reinterpret_cast<uint2*>(&Bs[jc * NI + (kg ^ ((jc & 7) << 3))]) = h; }
      STORE_COL(0, a00, a10, a20, a30);
      STORE_COL(1, a01, a11, a21, a31);
      STORE_COL(2, a02, a12, a22, a32);
      STORE_COL(3, a03, a13, a23, a33);
      #undef STORE_COL
    }
  };
  auto mfmaChunk = [&](int kc) {
    #pragma unroll
    for (int ks = 0; ks < 2; ++ks) {
      const int ka = ks * 32 + 8 * lk;            // k within As (64-col rows)
      const int kg = kc * 64 + ka;                // k within Bs (256-col rows)
      bf16x8 bfr[4];
      #pragma unroll
      for (int n = 0; n < 4; ++n) {
        int row = wc * 64 + n * 16 + l15;
        bfr[n] = *reinterpret_cast<const bf16x8*>(&Bs[row * NI + (kg ^ ((row & 7) << 3))]);
      }
      #pragma unroll
      for (int m = 0; m < 4; ++m) {
        int row = wr * 64 + m * 16 + l15;
        bf16x8 af = *reinterpret_cast<const bf16x8*>(&As[row * 64 + (ka ^ ((row & 7) << 3))]);
        #pragma unroll
        for (int n = 0; n < 4; ++n)
          C[m][n] = __builtin_amdgcn_mfma_f32_16x16x32_bf16(af, bfr[n], C[m][n], 0, 0, 0);
      }
    }
  };
  auto epilogue = [&](int bh) {
    float* obh = ob + (size_t)bh * BH * NJ;
    #pragma unroll
    for (int m = 0; m < 4; ++m) {
      int b0 = wr * 64 + m * 16 + lk * 4;
      #pragma unroll
      for (int n = 0; n < 4; ++n) {
        int j = wc * 64 + n * 16 + l15;
        float ls = logS[j];
        #pragma unroll
        for (int rr = 0; rr < 4; ++rr) {
          obh[(size_t)(b0 + rr) * NJ + j] = __logf(C[m][n][rr]) - ls;
        }
      }
    }
  };

  // ================= pass 1: b-rows 0..127, stage B persistently =================
  loadA(xb, 0);
  loadB(0);
  zeroC();
  for (int kc = 0; kc < 4; ++kc) {
    convA();
    convB(kc);
    __syncthreads();
    if (kc < 3) {            // loads fly across the MFMA phase and the barrier
      loadA(xb, kc + 1);
      loadB(kc + 1);
    } else {                 // prefetch pass-2 chunk 0 (A only)
      loadA(xb2, 0);
    }
    mfmaChunk(kc);
    __syncthreads();
  }

  // ---- column sums -> logS[j] (B was staged exactly once)
  {
    int jb = lane * 4;
    colpart[wid * NJ + jb + ((0 + r) & 3)] = bsum0;
    colpart[wid * NJ + jb + ((1 + r) & 3)] = bsum1;
    colpart[wid * NJ + jb + ((2 + r) & 3)] = bsum2;
    colpart[wid * NJ + jb + ((3 + r) & 3)] = bsum3;
  }
  __syncthreads();
  if (tid < NJ) {
    float s = 0.f;
    #pragma unroll
    for (int c = 0; c < 8; ++c) s += colpart[c * NJ + tid];
    logS[tid] = __logf(s);
  }
  __syncthreads();

  // ---- epilogue half 0 (pass-2 chunk-0 loads already in flight)
  epilogue(0);

  // ================= pass 2: b-rows 128..255 against resident Bs =================
  zeroC();
  for (int kc = 0; kc < 4; ++kc) {
    convA();
    __syncthreads();
    if (kc < 3) loadA(xb2, kc + 1);
    mfmaChunk(kc);
    __syncthreads();
  }

  epilogue(1);
}

extern "C" void kernel_launch(void* const* d_in, const int* in_sizes, int n_in,
                              void* d_out, int out_size, void* d_ws, size_t ws_size,
                              hipStream_t stream) {
  const float* x   = (const float*)d_in[0];
  const float* acc = (const float*)d_in[1];
  float* out = (float*)d_out;
  hipLaunchKernelGGL(densesum_kernel, dim3(256), dim3(512), 0, stream, x, acc, out);
}